// Round 3
// baseline (3244.778 us; speedup 1.0000x reference)
//
#include <hip/hip_runtime.h>
#include <hip/hip_bf16.h>
#include <cstddef>

// Problem constants
#define BB   16
#define LL   2048
#define DD   1024
#define SS   64
#define HH   512
#define H3   1536
#define NCLS 3
#define GPB  16   // WGs per batch in the GRU (each owns 32 of 512 hidden dims)

typedef _Float16 half2_t __attribute__((ext_vector_type(2)));
typedef _Float16 f16x8  __attribute__((ext_vector_type(8)));
typedef float    f32x4  __attribute__((ext_vector_type(4)));

static __device__ __forceinline__ half2_t u2h2(unsigned int u) {
    union { unsigned int u; half2_t h; } cv; cv.u = u; return cv.h;
}
static __device__ __forceinline__ unsigned short f2h(float f) {
    _Float16 h = (_Float16)f;
    union { _Float16 h; unsigned short u; } cv; cv.h = h; return cv.u;
}

// ---------------------------------------------------------------------------
// 1) Segment-mean pooling. One WG per (s,b); output (S,B,D) row r = s*16+b,
//    in fp32 (residual) AND f16 (GEMM input).
// ---------------------------------------------------------------------------
__global__ __launch_bounds__(256) void pool_kernel(
        const float* __restrict__ hs,      // (B, L, D)
        const int*   __restrict__ gidx,    // (B, L)
        float*       __restrict__ pooled,  // (S*B, D) fp32
        _Float16*    __restrict__ pooledh) // (S*B, D) f16
{
    const int r = blockIdx.x;
    const int b = r & 15;
    const int s = r >> 4;
    __shared__ int lst[LL];
    __shared__ int cnt;
    const int tid = threadIdx.x;
    if (tid == 0) cnt = 0;
    __syncthreads();
    const int* gi = gidx + b * LL;
    for (int l = tid; l < LL; l += 256) {
        if (gi[l] == s) { int p = atomicAdd(&cnt, 1); lst[p] = l; }
    }
    __syncthreads();
    const int c = cnt;
    const float* hb = hs + (size_t)b * LL * DD;
    const int d0 = tid * 4;
    float4 acc = make_float4(0.f, 0.f, 0.f, 0.f);
    for (int i = 0; i < c; ++i) {
        const float4 v = *(const float4*)(hb + (size_t)lst[i] * DD + d0);
        acc.x += v.x; acc.y += v.y; acc.z += v.z; acc.w += v.w;
    }
    const float inv = 1.0f / (float)c;
    float4 o = make_float4(acc.x * inv, acc.y * inv, acc.z * inv, acc.w * inv);
    *(float4*)(pooled + (size_t)r * DD + d0) = o;
    ushort4 oh;
    oh.x = f2h(o.x); oh.y = f2h(o.y); oh.z = f2h(o.z); oh.w = f2h(o.w);
    *(ushort4*)(pooledh + (size_t)r * DD + d0) = oh;
}

// ---------------------------------------------------------------------------
// 2) prep kernel: fused weight conversion + packing (one dispatch).
//    [0,256):    W_down  fp32->f16
//    [256,640):  W_ih0   fp32->f16
//    [640,896):  W_lin1  fp32->f16
//    [896,1664): pack W_hh0 -> wp0 (256 x 1536 u32, f16 k-pairs)
//    [1664,2432): pack W_hh1 -> wp1
//    [2432,2528): pack W_ih1 -> wip1 [16 slices][192 rows][128 words]
//                 row tr=2*(gate*32+jl)+half, word i: k = half*256+2i,
//                 col = gate*512 + p*32 + jl
// ---------------------------------------------------------------------------
__global__ __launch_bounds__(256) void prep_kernel(
        const float* __restrict__ a, _Float16* __restrict__ da,
        const float* __restrict__ b, _Float16* __restrict__ db,
        const float* __restrict__ c, _Float16* __restrict__ dc,
        const float* __restrict__ Whh0, unsigned int* __restrict__ wp0,
        const float* __restrict__ Whh1, unsigned int* __restrict__ wp1,
        const float* __restrict__ Wih1, unsigned int* __restrict__ wip1)
{
    __shared__ float tb[32][33];
    const int tid = threadIdx.x;
    int blk = blockIdx.x;
    if (blk < 896) {
        const float* s; _Float16* t;
        if (blk < 256)      { s = a; t = da; }
        else if (blk < 640) { s = b; t = db; blk -= 256; }
        else                { s = c; t = dc; blk -= 640; }
        const int i = (blk * 256 + tid) * 8;
        const float4 v0 = *(const float4*)(s + i);
        const float4 v1 = *(const float4*)(s + i + 4);
        ushort4 u0, u1;
        u0.x = f2h(v0.x); u0.y = f2h(v0.y); u0.z = f2h(v0.z); u0.w = f2h(v0.w);
        u1.x = f2h(v1.x); u1.y = f2h(v1.y); u1.z = f2h(v1.z); u1.w = f2h(v1.w);
        *(ushort4*)(t + i)     = u0;
        *(ushort4*)(t + i + 4) = u1;
        return;
    }
    if (blk < 2432) {
        const float*  W;
        unsigned int* Wp;
        int idx;
        if (blk < 1664) { W = Whh0; Wp = wp0; idx = blk - 896; }
        else            { W = Whh1; Wp = wp1; idx = blk - 1664; }
        const int bk = idx & 15;            // k-block (16)
        const int bg = idx >> 4;            // g-block (48)
        const int k0 = bk * 32, g0 = bg * 32;
        const int tx = tid & 31, ty = tid >> 5;
        for (int i = ty; i < 32; i += 8)
            tb[i][tx] = W[(size_t)(g0 + i) * HH + k0 + tx];
        __syncthreads();
        for (int i = ty; i < 16; i += 8) {
            const float lo = tb[tx][2 * i];
            const float hi = tb[tx][2 * i + 1];
            const unsigned int pk = (unsigned int)f2h(lo) | ((unsigned int)f2h(hi) << 16);
            Wp[(size_t)(k0 / 2 + i) * H3 + g0 + tx] = pk;
        }
        return;
    }
    // W_ih1 pack: 96 blocks, p = idx/6, chunk = idx%6, 16 words/thread
    {
        const int idx = blk - 2432;
        const int p = idx / 6, ch = idx % 6;
#pragma unroll
        for (int w = 0; w < 16; ++w) {
            const int wordid = ch * 4096 + tid * 16 + w;
            const int tr = wordid >> 7;
            const int i  = wordid & 127;
            const int rr = tr >> 1, hf = tr & 1;
            const int gate = rr >> 5, jl = rr & 31;
            const int col  = gate * HH + p * 32 + jl;
            const int k    = hf * 256 + 2 * i;
            const float lo = Wih1[(size_t)col * HH + k];
            const float hi = Wih1[(size_t)col * HH + k + 1];
            wip1[(size_t)p * 24576 + wordid] =
                (unsigned int)f2h(lo) | ((unsigned int)f2h(hi) << 16);
        }
    }
}

// ---------------------------------------------------------------------------
// 3) f16 MFMA GEMM: C[M,N] = A[M,K] @ W[N,K]^T + bias[N] (+resid, fp32 out)
//    or f16 out. 64x64 tile per WG (4 waves; wave w = 16-row strip), K-step 32.
// ---------------------------------------------------------------------------
template <bool F16OUT>
__global__ __launch_bounds__(256) void gemm_mfma_kernel(
        const _Float16* __restrict__ A,
        const _Float16* __restrict__ W,
        const float*    __restrict__ bias,
        const float*    __restrict__ resid,   // nullable, only for fp32 out
        void*           __restrict__ C,
        int M, int N, int K)
{
    const int tid  = threadIdx.x;
    const int wv   = tid >> 6;
    const int lane = tid & 63;
    const int m0 = blockIdx.y * 64 + wv * 16;
    const int n0 = blockIdx.x * 64;
    const int l15 = lane & 15;
    const int ko  = (lane >> 4) * 8;

    const _Float16* Ap = A + (size_t)(m0 + l15) * K + ko;
    const _Float16* Wpt = W + (size_t)(n0 + l15) * K + ko;

    f32x4 acc[4] = {};
    for (int k0 = 0; k0 < K; k0 += 32) {
        const f16x8 av = *(const f16x8*)(Ap + k0);
#pragma unroll
        for (int nb = 0; nb < 4; ++nb) {
            const f16x8 bq = *(const f16x8*)(Wpt + (size_t)nb * 16 * K + k0);
            acc[nb] = __builtin_amdgcn_mfma_f32_16x16x32_f16(av, bq, acc[nb], 0, 0, 0);
        }
    }
    const int crow = m0 + (lane >> 4) * 4;
#pragma unroll
    for (int nb = 0; nb < 4; ++nb) {
        const int col = n0 + nb * 16 + l15;
        const float bb = bias[col];
#pragma unroll
        for (int rg = 0; rg < 4; ++rg) {
            float v = acc[nb][rg] + bb;
            const size_t off = (size_t)(crow + rg) * N + col;
            if (F16OUT) {
                ((_Float16*)C)[off] = (_Float16)v;
            } else {
                if (resid) v += resid[off];
                ((float*)C)[off] = v;
            }
        }
    }
}

// ---------------------------------------------------------------------------
// 4) Fused two-layer GRU, v8. 256 WGs = (b,p); 65 iterations; iteration t
//    computes layer-0 step t and layer-1 step t-1 (1-step pipeline).
//    Layer-1's input projection (W_ih1 @ y0) is fused as extra dots on the
//    same polled h0 data -> the ih1 GEMM dispatch and ys0 stores vanish.
//    Weights per dot-thread: W_hh0 half-row (128 u32, regs/AGPR),
//    W_hh1 half-row (128 u32), W_ih1 quarter (64 u32) + rest in 48KB LDS
//    (XOR-swizzled, 8-way spread). Handshake: tagged 8B words (v7 scheme),
//    two buffers (h0, h1) polled concurrently.
// ---------------------------------------------------------------------------
__global__ __launch_bounds__(256) void gru_fused_kernel(
        const _Float16*     __restrict__ xW0,   // (S*B, 1536) f16 (layer-0 xW)
        const unsigned int* __restrict__ Wp0,   // (256, 1536) packed W_hh0
        const float*        __restrict__ bhh0,  // (1536)
        const unsigned int* __restrict__ Wp1,   // (256, 1536) packed W_hh1
        const float*        __restrict__ bhh1,  // (1536)
        const unsigned int* __restrict__ WIp,   // (16, 192, 128) packed W_ih1
        const float*        __restrict__ bih1,  // (1536)
        _Float16*           __restrict__ ys1,   // (S*B, 512) f16 (layer-1 out)
        unsigned long long* __restrict__ hbuf0, // [2][16][256] {tag,pk}
        unsigned long long* __restrict__ hbuf1) // [2][16][256] {tag,pk}
{
    __shared__ __align__(16) unsigned int h0ls[264];   // halves at 0 / 132
    __shared__ __align__(16) unsigned int h1ls[264];
    __shared__ __align__(16) uint4 wih[192 * 16];      // 48KB, swizzled q^(tr&7)
    __shared__ float dots0[96];
    __shared__ float dots1[128];   // r[0,32) z[32,64) n_x[64,96) n_h[96,128)

    const int wg  = blockIdx.x;
    const int b   = wg & 15;
    const int p   = wg >> 4;
    const int tid = threadIdx.x;

    const int tr   = tid;               // dot row-half id (tid<192)
    const int rr   = tid >> 1;
    const int half = tid & 1;
    const int gate = rr >> 5;
    const int jl   = rr & 31;
    const int col  = gate * HH + p * 32 + jl;

    float bias0 = 0.f, biasI = 0.f, biasH = 0.f;
    unsigned int w0[128], w1[128], wI[64];
    if (tid < 192) {
        bias0 = bhh0[col];
        biasI = bih1[col];
        biasH = bhh1[col];
#pragma unroll
        for (int i = 0; i < 128; ++i)
            w0[i] = Wp0[(size_t)(half * 128 + i) * H3 + col];
#pragma unroll
        for (int i = 0; i < 128; ++i)
            w1[i] = Wp1[(size_t)(half * 128 + i) * H3 + col];
        const uint4* g4 = (const uint4*)(WIp + (size_t)p * 24576) + tr * 32;
#pragma unroll
        for (int q = 0; q < 16; ++q) {
            const uint4 v = g4[q];
            wI[4 * q + 0] = v.x; wI[4 * q + 1] = v.y;
            wI[4 * q + 2] = v.z; wI[4 * q + 3] = v.w;
        }
    }
    {   // stage W_ih1 words 64..127 of each row into LDS (swizzled)
        const uint4* g4 = (const uint4*)(WIp + (size_t)p * 24576);
        for (int u = tid; u < 3072; u += 256) {
            const int trr = u >> 4, qq = u & 15;
            wih[trr * 16 + (qq ^ (trr & 7))] = g4[trr * 32 + 16 + qq];
        }
    }
    h0ls[tid] = 0u; h1ls[tid] = 0u;
    if (tid < 8) { h0ls[256 + tid] = 0u; h1ls[256 + tid] = 0u; }
    float h0_own = 0.f, h1_own = 0.f;
    __syncthreads();

    for (int t = 0; t <= SS; ++t) {
        // ---- layer-0 xW prefetch (no h dependency; hides under poll) ----
        float xr = 0.f, xz = 0.f, xn = 0.f;
        if (t < SS && tid < 32) {
            const int row = t * BB + b;
            const int j = p * 32 + tid;
            xr = (float)xW0[(size_t)row * H3 + j];
            xz = (float)xW0[(size_t)row * H3 + HH + j];
            xn = (float)xW0[(size_t)row * H3 + 2 * HH + j];
        }

        // ---- dual tagged poll: h0_{t-1} (tag t) and h1_{t-2} (tag t-1) ----
        {
            const unsigned long long* s0 =
                hbuf0 + ((size_t)(((t - 1) & 1) * BB + b)) * 256 + tid;
            const unsigned long long* s1 =
                hbuf1 + ((size_t)((t & 1) * BB + b)) * 256 + tid;
            unsigned long long v0 = 0ull, v1 = 0ull;
            bool d0 = (t == 0), d1 = (t <= 1);
            while (!(d0 && d1)) {
                unsigned long long a = 0ull, c = 0ull;
                if (!d0) a = __hip_atomic_load(s0, __ATOMIC_RELAXED,
                                               __HIP_MEMORY_SCOPE_AGENT);
                if (!d1) c = __hip_atomic_load(s1, __ATOMIC_RELAXED,
                                               __HIP_MEMORY_SCOPE_AGENT);
                if (!d0 && (unsigned int)(a >> 32) == (unsigned int)t) {
                    v0 = a; d0 = true;
                }
                if (!d1 && (unsigned int)(c >> 32) == (unsigned int)(t - 1)) {
                    v1 = c; d1 = true;
                }
                if (!(d0 && d1)) __builtin_amdgcn_s_sleep(1);
            }
            if (t > 0) h0ls[(tid >> 7) * 132 + (tid & 127)] = (unsigned int)v0;
            if (t > 1) h1ls[(tid >> 7) * 132 + (tid & 127)] = (unsigned int)v1;
        }
        __syncthreads();                                   // (A)

        // ---- dots: hh0 (h0), hh1 (h1), ih1 (h0); 192 threads ----
        if (tid < 192) {
            float A0 = 0.f, A1 = 0.f, A2 = 0.f, A3 = 0.f;   // hh0
            float B0 = 0.f, B1 = 0.f, B2 = 0.f, B3 = 0.f;   // hh1
            float C0 = 0.f, C1 = 0.f, C2 = 0.f, C3 = 0.f;   // ih1
            const uint4* h0p = (const uint4*)&h0ls[half * 132];
            const uint4* h1p = (const uint4*)&h1ls[half * 132];
            const uint4* wb  = &wih[tr * 16];
#pragma unroll
            for (int i = 0; i < 32; ++i) {
                const uint4 h0v = h0p[i];
                const uint4 h1v = h1p[i];
                A0 = __builtin_amdgcn_fdot2(u2h2(w0[4 * i + 0]), u2h2(h0v.x), A0, false);
                A1 = __builtin_amdgcn_fdot2(u2h2(w0[4 * i + 1]), u2h2(h0v.y), A1, false);
                A2 = __builtin_amdgcn_fdot2(u2h2(w0[4 * i + 2]), u2h2(h0v.z), A2, false);
                A3 = __builtin_amdgcn_fdot2(u2h2(w0[4 * i + 3]), u2h2(h0v.w), A3, false);
                B0 = __builtin_amdgcn_fdot2(u2h2(w1[4 * i + 0]), u2h2(h1v.x), B0, false);
                B1 = __builtin_amdgcn_fdot2(u2h2(w1[4 * i + 1]), u2h2(h1v.y), B1, false);
                B2 = __builtin_amdgcn_fdot2(u2h2(w1[4 * i + 2]), u2h2(h1v.z), B2, false);
                B3 = __builtin_amdgcn_fdot2(u2h2(w1[4 * i + 3]), u2h2(h1v.w), B3, false);
                uint4 wv;
                if (i < 16) {
                    wv.x = wI[4 * i + 0]; wv.y = wI[4 * i + 1];
                    wv.z = wI[4 * i + 2]; wv.w = wI[4 * i + 3];
                } else {
                    wv = wb[(i - 16) ^ (tr & 7)];
                }
                C0 = __builtin_amdgcn_fdot2(u2h2(wv.x), u2h2(h0v.x), C0, false);
                C1 = __builtin_amdgcn_fdot2(u2h2(wv.y), u2h2(h0v.y), C1, false);
                C2 = __builtin_amdgcn_fdot2(u2h2(wv.z), u2h2(h0v.z), C2, false);
                C3 = __builtin_amdgcn_fdot2(u2h2(wv.w), u2h2(h0v.w), C3, false);
            }
            float acc0 = (A0 + A1) + (A2 + A3);
            acc0 += __shfl_xor(acc0, 1, 64);
            if (half == 0) dots0[rr] = acc0 + bias0;
            float accH = (B0 + B1) + (B2 + B3);
            float accC = (C0 + C1) + (C2 + C3);
            if (gate < 2) {
                float s = accH + accC;
                s += __shfl_xor(s, 1, 64);
                if (half == 0) dots1[gate * 32 + jl] = s + biasI + biasH;
            } else {
                accC += __shfl_xor(accC, 1, 64);
                accH += __shfl_xor(accH, 1, 64);
                if (half == 0) {
                    dots1[64 + jl] = accC + biasI;
                    dots1[96 + jl] = accH + biasH;
                }
            }
        }
        __syncthreads();                                   // (B)

        // ---- layer-0 gates (wave0 lanes 0..31): step t ----
        if (t < SS && tid < 32) {
            const float ar = dots0[tid];
            const float az = dots0[32 + tid];
            const float an = dots0[64 + tid];
            const float rg = 1.f / (1.f + __expf(-(xr + ar)));
            const float zg = 1.f / (1.f + __expf(-(xz + az)));
            const float nn = xn + rg * an;
            const float e  = __expf(-2.f * nn);
            const float ng = (1.f - e) / (1.f + e);          // tanh
            const float hnew = (1.f - zg) * ng + zg * h0_own;
            h0_own = hnew;
            const float other = __shfl_xor(hnew, 1, 64);
            if ((tid & 1) == 0) {
                const unsigned int pk = (unsigned int)f2h(hnew)
                                      | ((unsigned int)f2h(other) << 16);
                const unsigned long long val =
                    ((unsigned long long)(unsigned int)(t + 1) << 32) | pk;
                __hip_atomic_store(
                    hbuf0 + ((size_t)((t & 1) * BB + b)) * 256 + p * 16 + (tid >> 1),
                    val, __ATOMIC_RELAXED, __HIP_MEMORY_SCOPE_AGENT);
            }
        }
        // ---- layer-1 gates (wave1 lanes 0..31): step t-1 ----
        if (t > 0 && tid >= 64 && tid < 96) {
            const int j = tid - 64;
            const float ar = dots1[j];
            const float az = dots1[32 + j];
            const float nx = dots1[64 + j];
            const float nh = dots1[96 + j];
            const float rg = 1.f / (1.f + __expf(-ar));
            const float zg = 1.f / (1.f + __expf(-az));
            const float nn = nx + rg * nh;
            const float e  = __expf(-2.f * nn);
            const float ng = (1.f - e) / (1.f + e);          // tanh
            const float hnew = (1.f - zg) * ng + zg * h1_own;
            h1_own = hnew;
            ys1[(size_t)((t - 1) * BB + b) * HH + p * 32 + j] = (_Float16)hnew;
            const float other = __shfl_xor(hnew, 1, 64);
            if ((j & 1) == 0) {
                const unsigned int pk = (unsigned int)f2h(hnew)
                                      | ((unsigned int)f2h(other) << 16);
                const unsigned long long val =
                    ((unsigned long long)(unsigned int)t << 32) | pk;
                __hip_atomic_store(
                    hbuf1 + ((size_t)(((t - 1) & 1) * BB + b)) * 256 + p * 16 + (j >> 1),
                    val, __ATOMIC_RELAXED, __HIP_MEMORY_SCOPE_AGENT);
            }
        }
        // no trailing barrier: next iteration's LDS writes are ordered by the
        // poll (needs own WG's tags) and barrier (A); dots are reused only
        // after (A) of the next iteration.
    }
}

// ---------------------------------------------------------------------------
// 5) Fused LayerNorm + classification head. One WG per output row.
// ---------------------------------------------------------------------------
__global__ __launch_bounds__(256) void ln_head_kernel(
        const float* __restrict__ X,      // (S*B, D), row = s*16+b
        const float* __restrict__ gamma,
        const float* __restrict__ beta,
        const float* __restrict__ Wh,     // (3, 1024)
        const float* __restrict__ bh,     // (3)
        float*       __restrict__ out)    // (B*S, 3)
{
    __shared__ float red[12];
    const int r  = blockIdx.x;            // b*64 + s
    const int bI = r >> 6;
    const int s  = r & 63;
    const float* x = X + (size_t)(s * BB + bI) * DD;
    const int tid = threadIdx.x;
    const float4 v = *(const float4*)(x + tid * 4);
    float sum = v.x + v.y + v.z + v.w;
    float ss  = v.x * v.x + v.y * v.y + v.z * v.z + v.w * v.w;
#pragma unroll
    for (int o = 32; o > 0; o >>= 1) {
        sum += __shfl_down(sum, o, 64);
        ss  += __shfl_down(ss,  o, 64);
    }
    const int lane = tid & 63, w = tid >> 6;
    if (lane == 0) { red[w] = sum; red[4 + w] = ss; }
    __syncthreads();
    const float tsum = red[0] + red[1] + red[2] + red[3];
    const float tss  = red[4] + red[5] + red[6] + red[7];
    const float mu  = tsum * (1.f / (float)DD);
    const float var = tss * (1.f / (float)DD) - mu * mu;
    const float inv = rsqrtf(var + 1e-5f);
    const float4 g  = *(const float4*)(gamma + tid * 4);
    const float4 be = *(const float4*)(beta + tid * 4);
    float y0 = (v.x - mu) * inv * g.x + be.x;
    float y1 = (v.y - mu) * inv * g.y + be.y;
    float y2 = (v.z - mu) * inv * g.z + be.z;
    float y3 = (v.w - mu) * inv * g.w + be.w;
    const float4 w0 = *(const float4*)(Wh + 0 * DD + tid * 4);
    const float4 w1 = *(const float4*)(Wh + 1 * DD + tid * 4);
    const float4 w2 = *(const float4*)(Wh + 2 * DD + tid * 4);
    float p0 = y0 * w0.x + y1 * w0.y + y2 * w0.z + y3 * w0.w;
    float p1 = y0 * w1.x + y1 * w1.y + y2 * w1.z + y3 * w1.w;
    float p2 = y0 * w2.x + y1 * w2.y + y2 * w2.z + y3 * w2.w;
#pragma unroll
    for (int o = 32; o > 0; o >>= 1) {
        p0 += __shfl_down(p0, o, 64);
        p1 += __shfl_down(p1, o, 64);
        p2 += __shfl_down(p2, o, 64);
    }
    __syncthreads();
    if (lane == 0) { red[w] = p0; red[4 + w] = p1; red[8 + w] = p2; }
    __syncthreads();
    if (tid == 0) {
        out[(size_t)r * NCLS + 0] = red[0] + red[1] + red[2]  + red[3]  + bh[0];
        out[(size_t)r * NCLS + 1] = red[4] + red[5] + red[6]  + red[7]  + bh[1];
        out[(size_t)r * NCLS + 2] = red[8] + red[9] + red[10] + red[11] + bh[2];
    }
}

// ---------------------------------------------------------------------------
extern "C" void kernel_launch(void* const* d_in, const int* in_sizes, int n_in,
                              void* d_out, int out_size, void* d_ws, size_t ws_size,
                              hipStream_t stream) {
    const float* hs      = (const float*)d_in[0];
    const float* W_down  = (const float*)d_in[1];
    const float* b_down  = (const float*)d_in[2];
    const float* W_ih0   = (const float*)d_in[3];
    const float* W_hh0   = (const float*)d_in[4];
    const float* b_ih0   = (const float*)d_in[5];
    const float* b_hh0   = (const float*)d_in[6];
    const float* W_ih1   = (const float*)d_in[7];
    const float* W_hh1   = (const float*)d_in[8];
    const float* b_ih1   = (const float*)d_in[9];
    const float* b_hh1   = (const float*)d_in[10];
    const float* W_lin1  = (const float*)d_in[11];
    const float* b_lin1  = (const float*)d_in[12];
    const float* gamma   = (const float*)d_in[13];
    const float* beta    = (const float*)d_in[14];
    const float* W_head  = (const float*)d_in[15];
    const float* b_head  = (const float*)d_in[16];
    const int*   gidx    = (const int*)d_in[17];
    float* out = (float*)d_out;

    char* ws = (char*)d_ws;
    const size_t MB = (size_t)1 << 20;
    float*        pooled   = (float*)(ws);                        // 4 MB fp32
    _Float16*     pooledh  = (_Float16*)(ws + 4 * MB);            // 2 MB
    _Float16*     xd_h     = (_Float16*)(ws + 6 * MB);            // 1 MB
    _Float16*     xW_h     = (_Float16*)(ws + 7 * MB);            // 3 MB
    _Float16*     ys1_h    = (_Float16*)(ws + 10 * MB);           // 1 MB
    float*        xln      = (float*)(ws + 11 * MB);              // 4 MB
    unsigned int* wp0      = (unsigned int*)(ws + 15 * MB);       // 1.5 MB
    unsigned int* wp1      = (unsigned int*)(ws + 15 * MB + 1536 * 1024); // 1.5 MB
    _Float16*     wdown_h  = (_Float16*)(ws + 18 * MB);           // 1 MB
    _Float16*     wih0_h   = (_Float16*)(ws + 19 * MB);           // 1.5 MB
    unsigned int* wip1     = (unsigned int*)(ws + 19 * MB + 1536 * 1024); // 1.5 MB
    _Float16*     wlin1_h  = (_Float16*)(ws + 22 * MB);           // 1 MB
    unsigned long long* hbuf0 = (unsigned long long*)(ws + 23 * MB); // 64 KB
    unsigned long long* hbuf1 = hbuf0 + 2 * BB * 256;                // 64 KB

    // zero the tagged h-exchange buffers (ws is poisoned before every launch;
    // garbage could alias a valid tag). 128 KB total.
    hipMemsetAsync(hbuf0, 0, 2 * 2 * BB * 256 * sizeof(unsigned long long), stream);

    // 1) pooling: fp32 residual + f16 GEMM input, layout (S,B,D)
    pool_kernel<<<BB * SS, 256, 0, stream>>>(hs, gidx, pooled, pooledh);

    // 2) fused weight prep (one dispatch)
    prep_kernel<<<2528, 256, 0, stream>>>(W_down, wdown_h, W_ih0, wih0_h,
                                          W_lin1, wlin1_h,
                                          W_hh0, wp0, W_hh1, wp1,
                                          W_ih1, wip1);

    // 3) down-projection: xd = pooled @ W_down^T + b_down  (f16 out)
    gemm_mfma_kernel<true><<<dim3(HH / 64, (SS * BB) / 64), 256, 0, stream>>>(
        pooledh, wdown_h, b_down, nullptr, xd_h, SS * BB, HH, DD);

    // 4) layer-0 input projection: xW = xd @ W_ih0^T + b_ih0  (f16 out)
    gemm_mfma_kernel<true><<<dim3(H3 / 64, (SS * BB) / 64), 256, 0, stream>>>(
        xd_h, wih0_h, b_ih0, nullptr, xW_h, SS * BB, H3, HH);

    // 5) fused two-layer recurrence (replaces gru0 + ih1 GEMM + gru1)
    gru_fused_kernel<<<BB * GPB, 256, 0, stream>>>(
        xW_h, wp0, b_hh0, wp1, b_hh1, wip1, b_ih1, ys1_h, hbuf0, hbuf1);

    // 6) up-projection + residual: xln = pooled + ys1 @ W_lin1^T + b_lin1 (fp32)
    gemm_mfma_kernel<false><<<dim3(DD / 64, (SS * BB) / 64), 256, 0, stream>>>(
        ys1_h, wlin1_h, b_lin1, pooled, xln, SS * BB, DD, HH);

    // 7) LayerNorm + head
    ln_head_kernel<<<BB * SS, 256, 0, stream>>>(xln, gamma, beta, W_head, b_head, out);
}

// Round 4
// 3223.821 us; speedup vs baseline: 1.0065x; 1.0065x over previous
//
#include <hip/hip_runtime.h>
#include <hip/hip_bf16.h>
#include <cstddef>

// Problem constants
#define BB   16
#define LL   2048
#define DD   1024
#define SS   64
#define HH   512
#define H3   1536
#define NCLS 3
#define GPB  16   // WGs per batch in the GRU (each owns 32 of 512 hidden dims)

typedef _Float16 half2_t __attribute__((ext_vector_type(2)));
typedef _Float16 f16x8  __attribute__((ext_vector_type(8)));
typedef float    f32x4  __attribute__((ext_vector_type(4)));

static __device__ __forceinline__ half2_t u2h2(unsigned int u) {
    union { unsigned int u; half2_t h; } cv; cv.u = u; return cv.h;
}
static __device__ __forceinline__ unsigned short f2h(float f) {
    _Float16 h = (_Float16)f;
    union { _Float16 h; unsigned short u; } cv; cv.h = h; return cv.u;
}

// ---------------------------------------------------------------------------
// 1) Segment-mean pooling. One WG per (s,b); output (S,B,D) row r = s*16+b,
//    in fp32 (residual) AND f16 (GEMM input).
// ---------------------------------------------------------------------------
__global__ __launch_bounds__(256) void pool_kernel(
        const float* __restrict__ hs,      // (B, L, D)
        const int*   __restrict__ gidx,    // (B, L)
        float*       __restrict__ pooled,  // (S*B, D) fp32
        _Float16*    __restrict__ pooledh) // (S*B, D) f16
{
    const int r = blockIdx.x;
    const int b = r & 15;
    const int s = r >> 4;
    __shared__ int lst[LL];
    __shared__ int cnt;
    const int tid = threadIdx.x;
    if (tid == 0) cnt = 0;
    __syncthreads();
    const int* gi = gidx + b * LL;
    for (int l = tid; l < LL; l += 256) {
        if (gi[l] == s) { int p = atomicAdd(&cnt, 1); lst[p] = l; }
    }
    __syncthreads();
    const int c = cnt;
    const float* hb = hs + (size_t)b * LL * DD;
    const int d0 = tid * 4;
    float4 acc = make_float4(0.f, 0.f, 0.f, 0.f);
    for (int i = 0; i < c; ++i) {
        const float4 v = *(const float4*)(hb + (size_t)lst[i] * DD + d0);
        acc.x += v.x; acc.y += v.y; acc.z += v.z; acc.w += v.w;
    }
    const float inv = 1.0f / (float)c;
    float4 o = make_float4(acc.x * inv, acc.y * inv, acc.z * inv, acc.w * inv);
    *(float4*)(pooled + (size_t)r * DD + d0) = o;
    ushort4 oh;
    oh.x = f2h(o.x); oh.y = f2h(o.y); oh.z = f2h(o.z); oh.w = f2h(o.w);
    *(ushort4*)(pooledh + (size_t)r * DD + d0) = oh;
}

// ---------------------------------------------------------------------------
// 2) prep kernel: fused weight conversion + packing (one dispatch).
//    [0,256):    W_down  fp32->f16
//    [256,640):  W_ih0   fp32->f16
//    [640,896):  W_lin1  fp32->f16
//    [896,1664): pack W_hh0 -> wp0 (256 x 1536 u32, f16 k-pairs)
//    [1664,2432): pack W_hh1 -> wp1
//    [2432,2528): pack W_ih1 -> wip1 [16 slices][192 rows][128 words]
//                 row tr=2*(gate*32+jl)+half, word i: k = half*256+2i,
//                 col = gate*512 + p*32 + jl
// ---------------------------------------------------------------------------
__global__ __launch_bounds__(256) void prep_kernel(
        const float* __restrict__ a, _Float16* __restrict__ da,
        const float* __restrict__ b, _Float16* __restrict__ db,
        const float* __restrict__ c, _Float16* __restrict__ dc,
        const float* __restrict__ Whh0, unsigned int* __restrict__ wp0,
        const float* __restrict__ Whh1, unsigned int* __restrict__ wp1,
        const float* __restrict__ Wih1, unsigned int* __restrict__ wip1)
{
    __shared__ float tb[32][33];
    const int tid = threadIdx.x;
    int blk = blockIdx.x;
    if (blk < 896) {
        const float* s; _Float16* t;
        if (blk < 256)      { s = a; t = da; }
        else if (blk < 640) { s = b; t = db; blk -= 256; }
        else                { s = c; t = dc; blk -= 640; }
        const int i = (blk * 256 + tid) * 8;
        const float4 v0 = *(const float4*)(s + i);
        const float4 v1 = *(const float4*)(s + i + 4);
        ushort4 u0, u1;
        u0.x = f2h(v0.x); u0.y = f2h(v0.y); u0.z = f2h(v0.z); u0.w = f2h(v0.w);
        u1.x = f2h(v1.x); u1.y = f2h(v1.y); u1.z = f2h(v1.z); u1.w = f2h(v1.w);
        *(ushort4*)(t + i)     = u0;
        *(ushort4*)(t + i + 4) = u1;
        return;
    }
    if (blk < 2432) {
        const float*  W;
        unsigned int* Wp;
        int idx;
        if (blk < 1664) { W = Whh0; Wp = wp0; idx = blk - 896; }
        else            { W = Whh1; Wp = wp1; idx = blk - 1664; }
        const int bk = idx & 15;            // k-block (16)
        const int bg = idx >> 4;            // g-block (48)
        const int k0 = bk * 32, g0 = bg * 32;
        const int tx = tid & 31, ty = tid >> 5;
        for (int i = ty; i < 32; i += 8)
            tb[i][tx] = W[(size_t)(g0 + i) * HH + k0 + tx];
        __syncthreads();
        for (int i = ty; i < 16; i += 8) {
            const float lo = tb[tx][2 * i];
            const float hi = tb[tx][2 * i + 1];
            const unsigned int pk = (unsigned int)f2h(lo) | ((unsigned int)f2h(hi) << 16);
            Wp[(size_t)(k0 / 2 + i) * H3 + g0 + tx] = pk;
        }
        return;
    }
    // W_ih1 pack: 96 blocks, p = idx/6, chunk = idx%6, 16 words/thread
    {
        const int idx = blk - 2432;
        const int p = idx / 6, ch = idx % 6;
#pragma unroll
        for (int w = 0; w < 16; ++w) {
            const int wordid = ch * 4096 + tid * 16 + w;
            const int tr = wordid >> 7;
            const int i  = wordid & 127;
            const int rr = tr >> 1, hf = tr & 1;
            const int gate = rr >> 5, jl = rr & 31;
            const int col  = gate * HH + p * 32 + jl;
            const int k    = hf * 256 + 2 * i;
            const float lo = Wih1[(size_t)col * HH + k];
            const float hi = Wih1[(size_t)col * HH + k + 1];
            wip1[(size_t)p * 24576 + wordid] =
                (unsigned int)f2h(lo) | ((unsigned int)f2h(hi) << 16);
        }
    }
}

// ---------------------------------------------------------------------------
// 3) f16 MFMA GEMM: C[M,N] = A[M,K] @ W[N,K]^T + bias[N] (+resid, fp32 out)
//    or f16 out. 64x64 tile per WG (4 waves; wave w = 16-row strip), K-step 32.
// ---------------------------------------------------------------------------
template <bool F16OUT>
__global__ __launch_bounds__(256) void gemm_mfma_kernel(
        const _Float16* __restrict__ A,
        const _Float16* __restrict__ W,
        const float*    __restrict__ bias,
        const float*    __restrict__ resid,   // nullable, only for fp32 out
        void*           __restrict__ C,
        int M, int N, int K)
{
    const int tid  = threadIdx.x;
    const int wv   = tid >> 6;
    const int lane = tid & 63;
    const int m0 = blockIdx.y * 64 + wv * 16;
    const int n0 = blockIdx.x * 64;
    const int l15 = lane & 15;
    const int ko  = (lane >> 4) * 8;

    const _Float16* Ap = A + (size_t)(m0 + l15) * K + ko;
    const _Float16* Wpt = W + (size_t)(n0 + l15) * K + ko;

    f32x4 acc[4] = {};
    for (int k0 = 0; k0 < K; k0 += 32) {
        const f16x8 av = *(const f16x8*)(Ap + k0);
#pragma unroll
        for (int nb = 0; nb < 4; ++nb) {
            const f16x8 bq = *(const f16x8*)(Wpt + (size_t)nb * 16 * K + k0);
            acc[nb] = __builtin_amdgcn_mfma_f32_16x16x32_f16(av, bq, acc[nb], 0, 0, 0);
        }
    }
    const int crow = m0 + (lane >> 4) * 4;
#pragma unroll
    for (int nb = 0; nb < 4; ++nb) {
        const int col = n0 + nb * 16 + l15;
        const float bb = bias[col];
#pragma unroll
        for (int rg = 0; rg < 4; ++rg) {
            float v = acc[nb][rg] + bb;
            const size_t off = (size_t)(crow + rg) * N + col;
            if (F16OUT) {
                ((_Float16*)C)[off] = (_Float16)v;
            } else {
                if (resid) v += resid[off];
                ((float*)C)[off] = v;
            }
        }
    }
}

// ---------------------------------------------------------------------------
// 4) Fused two-layer GRU, v9 = v8 + __launch_bounds__(256, 1).
//    The second arg (min 1 wave/EU -> 1 WG/CU) unlocks the full 512-reg
//    unified VGPR/AGPR budget so w0[128]+w1[128]+wI[64] (320 dwords) live in
//    registers/AGPRs instead of scratch (v8: VGPR capped at 256, ~460 MB of
//    spill traffic per dispatch, 2930 us).
//    Structure: 256 WGs = (b,p); 65 iterations; iteration t computes layer-0
//    step t and layer-1 step t-1 (1-step pipeline). Layer-1's input
//    projection (W_ih1 @ y0) is fused as extra dots on the same polled h0.
//    Handshake: tagged 8B words (v7 scheme), two buffers polled concurrently.
// ---------------------------------------------------------------------------
__global__ __launch_bounds__(256, 1) void gru_fused_kernel(
        const _Float16*     __restrict__ xW0,   // (S*B, 1536) f16 (layer-0 xW)
        const unsigned int* __restrict__ Wp0,   // (256, 1536) packed W_hh0
        const float*        __restrict__ bhh0,  // (1536)
        const unsigned int* __restrict__ Wp1,   // (256, 1536) packed W_hh1
        const float*        __restrict__ bhh1,  // (1536)
        const unsigned int* __restrict__ WIp,   // (16, 192, 128) packed W_ih1
        const float*        __restrict__ bih1,  // (1536)
        _Float16*           __restrict__ ys1,   // (S*B, 512) f16 (layer-1 out)
        unsigned long long* __restrict__ hbuf0, // [2][16][256] {tag,pk}
        unsigned long long* __restrict__ hbuf1) // [2][16][256] {tag,pk}
{
    __shared__ __align__(16) unsigned int h0ls[264];   // halves at 0 / 132
    __shared__ __align__(16) unsigned int h1ls[264];
    __shared__ __align__(16) uint4 wih[192 * 16];      // 48KB, swizzled q^(tr&7)
    __shared__ float dots0[96];
    __shared__ float dots1[128];   // r[0,32) z[32,64) n_x[64,96) n_h[96,128)

    const int wg  = blockIdx.x;
    const int b   = wg & 15;
    const int p   = wg >> 4;
    const int tid = threadIdx.x;

    const int tr   = tid;               // dot row-half id (tid<192)
    const int rr   = tid >> 1;
    const int half = tid & 1;
    const int gate = rr >> 5;
    const int jl   = rr & 31;
    const int col  = gate * HH + p * 32 + jl;

    float bias0 = 0.f, biasI = 0.f, biasH = 0.f;
    unsigned int w0[128], w1[128], wI[64];
    if (tid < 192) {
        bias0 = bhh0[col];
        biasI = bih1[col];
        biasH = bhh1[col];
#pragma unroll
        for (int i = 0; i < 128; ++i)
            w0[i] = Wp0[(size_t)(half * 128 + i) * H3 + col];
#pragma unroll
        for (int i = 0; i < 128; ++i)
            w1[i] = Wp1[(size_t)(half * 128 + i) * H3 + col];
        const uint4* g4 = (const uint4*)(WIp + (size_t)p * 24576) + tr * 32;
#pragma unroll
        for (int q = 0; q < 16; ++q) {
            const uint4 v = g4[q];
            wI[4 * q + 0] = v.x; wI[4 * q + 1] = v.y;
            wI[4 * q + 2] = v.z; wI[4 * q + 3] = v.w;
        }
    }
    {   // stage W_ih1 words 64..127 of each row into LDS (swizzled)
        const uint4* g4 = (const uint4*)(WIp + (size_t)p * 24576);
        for (int u = tid; u < 3072; u += 256) {
            const int trr = u >> 4, qq = u & 15;
            wih[trr * 16 + (qq ^ (trr & 7))] = g4[trr * 32 + 16 + qq];
        }
    }
    h0ls[tid] = 0u; h1ls[tid] = 0u;
    if (tid < 8) { h0ls[256 + tid] = 0u; h1ls[256 + tid] = 0u; }
    float h0_own = 0.f, h1_own = 0.f;
    __syncthreads();

    for (int t = 0; t <= SS; ++t) {
        // ---- layer-0 xW prefetch (no h dependency; hides under poll) ----
        float xr = 0.f, xz = 0.f, xn = 0.f;
        if (t < SS && tid < 32) {
            const int row = t * BB + b;
            const int j = p * 32 + tid;
            xr = (float)xW0[(size_t)row * H3 + j];
            xz = (float)xW0[(size_t)row * H3 + HH + j];
            xn = (float)xW0[(size_t)row * H3 + 2 * HH + j];
        }

        // ---- dual tagged poll: h0_{t-1} (tag t) and h1_{t-2} (tag t-1) ----
        {
            const unsigned long long* s0 =
                hbuf0 + ((size_t)(((t - 1) & 1) * BB + b)) * 256 + tid;
            const unsigned long long* s1 =
                hbuf1 + ((size_t)((t & 1) * BB + b)) * 256 + tid;
            unsigned long long v0 = 0ull, v1 = 0ull;
            bool d0 = (t == 0), d1 = (t <= 1);
            while (!(d0 && d1)) {
                unsigned long long a = 0ull, c = 0ull;
                if (!d0) a = __hip_atomic_load(s0, __ATOMIC_RELAXED,
                                               __HIP_MEMORY_SCOPE_AGENT);
                if (!d1) c = __hip_atomic_load(s1, __ATOMIC_RELAXED,
                                               __HIP_MEMORY_SCOPE_AGENT);
                if (!d0 && (unsigned int)(a >> 32) == (unsigned int)t) {
                    v0 = a; d0 = true;
                }
                if (!d1 && (unsigned int)(c >> 32) == (unsigned int)(t - 1)) {
                    v1 = c; d1 = true;
                }
                if (!(d0 && d1)) __builtin_amdgcn_s_sleep(1);
            }
            if (t > 0) h0ls[(tid >> 7) * 132 + (tid & 127)] = (unsigned int)v0;
            if (t > 1) h1ls[(tid >> 7) * 132 + (tid & 127)] = (unsigned int)v1;
        }
        __syncthreads();                                   // (A)

        // ---- dots: hh0 (h0), hh1 (h1), ih1 (h0); 192 threads ----
        if (tid < 192) {
            float A0 = 0.f, A1 = 0.f, A2 = 0.f, A3 = 0.f;   // hh0
            float B0 = 0.f, B1 = 0.f, B2 = 0.f, B3 = 0.f;   // hh1
            float C0 = 0.f, C1 = 0.f, C2 = 0.f, C3 = 0.f;   // ih1
            const uint4* h0p = (const uint4*)&h0ls[half * 132];
            const uint4* h1p = (const uint4*)&h1ls[half * 132];
            const uint4* wb  = &wih[tr * 16];
#pragma unroll
            for (int i = 0; i < 32; ++i) {
                const uint4 h0v = h0p[i];
                const uint4 h1v = h1p[i];
                A0 = __builtin_amdgcn_fdot2(u2h2(w0[4 * i + 0]), u2h2(h0v.x), A0, false);
                A1 = __builtin_amdgcn_fdot2(u2h2(w0[4 * i + 1]), u2h2(h0v.y), A1, false);
                A2 = __builtin_amdgcn_fdot2(u2h2(w0[4 * i + 2]), u2h2(h0v.z), A2, false);
                A3 = __builtin_amdgcn_fdot2(u2h2(w0[4 * i + 3]), u2h2(h0v.w), A3, false);
                B0 = __builtin_amdgcn_fdot2(u2h2(w1[4 * i + 0]), u2h2(h1v.x), B0, false);
                B1 = __builtin_amdgcn_fdot2(u2h2(w1[4 * i + 1]), u2h2(h1v.y), B1, false);
                B2 = __builtin_amdgcn_fdot2(u2h2(w1[4 * i + 2]), u2h2(h1v.z), B2, false);
                B3 = __builtin_amdgcn_fdot2(u2h2(w1[4 * i + 3]), u2h2(h1v.w), B3, false);
                uint4 wv;
                if (i < 16) {
                    wv.x = wI[4 * i + 0]; wv.y = wI[4 * i + 1];
                    wv.z = wI[4 * i + 2]; wv.w = wI[4 * i + 3];
                } else {
                    wv = wb[(i - 16) ^ (tr & 7)];
                }
                C0 = __builtin_amdgcn_fdot2(u2h2(wv.x), u2h2(h0v.x), C0, false);
                C1 = __builtin_amdgcn_fdot2(u2h2(wv.y), u2h2(h0v.y), C1, false);
                C2 = __builtin_amdgcn_fdot2(u2h2(wv.z), u2h2(h0v.z), C2, false);
                C3 = __builtin_amdgcn_fdot2(u2h2(wv.w), u2h2(h0v.w), C3, false);
            }
            float acc0 = (A0 + A1) + (A2 + A3);
            acc0 += __shfl_xor(acc0, 1, 64);
            if (half == 0) dots0[rr] = acc0 + bias0;
            float accH = (B0 + B1) + (B2 + B3);
            float accC = (C0 + C1) + (C2 + C3);
            if (gate < 2) {
                float s = accH + accC;
                s += __shfl_xor(s, 1, 64);
                if (half == 0) dots1[gate * 32 + jl] = s + biasI + biasH;
            } else {
                accC += __shfl_xor(accC, 1, 64);
                accH += __shfl_xor(accH, 1, 64);
                if (half == 0) {
                    dots1[64 + jl] = accC + biasI;
                    dots1[96 + jl] = accH + biasH;
                }
            }
        }
        __syncthreads();                                   // (B)

        // ---- layer-0 gates (wave0 lanes 0..31): step t ----
        if (t < SS && tid < 32) {
            const float ar = dots0[tid];
            const float az = dots0[32 + tid];
            const float an = dots0[64 + tid];
            const float rg = 1.f / (1.f + __expf(-(xr + ar)));
            const float zg = 1.f / (1.f + __expf(-(xz + az)));
            const float nn = xn + rg * an;
            const float e  = __expf(-2.f * nn);
            const float ng = (1.f - e) / (1.f + e);          // tanh
            const float hnew = (1.f - zg) * ng + zg * h0_own;
            h0_own = hnew;
            const float other = __shfl_xor(hnew, 1, 64);
            if ((tid & 1) == 0) {
                const unsigned int pk = (unsigned int)f2h(hnew)
                                      | ((unsigned int)f2h(other) << 16);
                const unsigned long long val =
                    ((unsigned long long)(unsigned int)(t + 1) << 32) | pk;
                __hip_atomic_store(
                    hbuf0 + ((size_t)((t & 1) * BB + b)) * 256 + p * 16 + (tid >> 1),
                    val, __ATOMIC_RELAXED, __HIP_MEMORY_SCOPE_AGENT);
            }
        }
        // ---- layer-1 gates (wave1 lanes 0..31): step t-1 ----
        if (t > 0 && tid >= 64 && tid < 96) {
            const int j = tid - 64;
            const float ar = dots1[j];
            const float az = dots1[32 + j];
            const float nx = dots1[64 + j];
            const float nh = dots1[96 + j];
            const float rg = 1.f / (1.f + __expf(-ar));
            const float zg = 1.f / (1.f + __expf(-az));
            const float nn = nx + rg * nh;
            const float e  = __expf(-2.f * nn);
            const float ng = (1.f - e) / (1.f + e);          // tanh
            const float hnew = (1.f - zg) * ng + zg * h1_own;
            h1_own = hnew;
            ys1[(size_t)((t - 1) * BB + b) * HH + p * 32 + j] = (_Float16)hnew;
            const float other = __shfl_xor(hnew, 1, 64);
            if ((j & 1) == 0) {
                const unsigned int pk = (unsigned int)f2h(hnew)
                                      | ((unsigned int)f2h(other) << 16);
                const unsigned long long val =
                    ((unsigned long long)(unsigned int)t << 32) | pk;
                __hip_atomic_store(
                    hbuf1 + ((size_t)(((t - 1) & 1) * BB + b)) * 256 + p * 16 + (j >> 1),
                    val, __ATOMIC_RELAXED, __HIP_MEMORY_SCOPE_AGENT);
            }
        }
        // no trailing barrier: next iteration's LDS writes are ordered by the
        // poll (needs own WG's tags) and barrier (A); dots are reused only
        // after (A) of the next iteration.
    }
}

// ---------------------------------------------------------------------------
// 5) Fused LayerNorm + classification head. One WG per output row.
// ---------------------------------------------------------------------------
__global__ __launch_bounds__(256) void ln_head_kernel(
        const float* __restrict__ X,      // (S*B, D), row = s*16+b
        const float* __restrict__ gamma,
        const float* __restrict__ beta,
        const float* __restrict__ Wh,     // (3, 1024)
        const float* __restrict__ bh,     // (3)
        float*       __restrict__ out)    // (B*S, 3)
{
    __shared__ float red[12];
    const int r  = blockIdx.x;            // b*64 + s
    const int bI = r >> 6;
    const int s  = r & 63;
    const float* x = X + (size_t)(s * BB + bI) * DD;
    const int tid = threadIdx.x;
    const float4 v = *(const float4*)(x + tid * 4);
    float sum = v.x + v.y + v.z + v.w;
    float ss  = v.x * v.x + v.y * v.y + v.z * v.z + v.w * v.w;
#pragma unroll
    for (int o = 32; o > 0; o >>= 1) {
        sum += __shfl_down(sum, o, 64);
        ss  += __shfl_down(ss,  o, 64);
    }
    const int lane = tid & 63, w = tid >> 6;
    if (lane == 0) { red[w] = sum; red[4 + w] = ss; }
    __syncthreads();
    const float tsum = red[0] + red[1] + red[2] + red[3];
    const float tss  = red[4] + red[5] + red[6] + red[7];
    const float mu  = tsum * (1.f / (float)DD);
    const float var = tss * (1.f / (float)DD) - mu * mu;
    const float inv = rsqrtf(var + 1e-5f);
    const float4 g  = *(const float4*)(gamma + tid * 4);
    const float4 be = *(const float4*)(beta + tid * 4);
    float y0 = (v.x - mu) * inv * g.x + be.x;
    float y1 = (v.y - mu) * inv * g.y + be.y;
    float y2 = (v.z - mu) * inv * g.z + be.z;
    float y3 = (v.w - mu) * inv * g.w + be.w;
    const float4 w0 = *(const float4*)(Wh + 0 * DD + tid * 4);
    const float4 w1 = *(const float4*)(Wh + 1 * DD + tid * 4);
    const float4 w2 = *(const float4*)(Wh + 2 * DD + tid * 4);
    float p0 = y0 * w0.x + y1 * w0.y + y2 * w0.z + y3 * w0.w;
    float p1 = y0 * w1.x + y1 * w1.y + y2 * w1.z + y3 * w1.w;
    float p2 = y0 * w2.x + y1 * w2.y + y2 * w2.z + y3 * w2.w;
#pragma unroll
    for (int o = 32; o > 0; o >>= 1) {
        p0 += __shfl_down(p0, o, 64);
        p1 += __shfl_down(p1, o, 64);
        p2 += __shfl_down(p2, o, 64);
    }
    __syncthreads();
    if (lane == 0) { red[w] = p0; red[4 + w] = p1; red[8 + w] = p2; }
    __syncthreads();
    if (tid == 0) {
        out[(size_t)r * NCLS + 0] = red[0] + red[1] + red[2]  + red[3]  + bh[0];
        out[(size_t)r * NCLS + 1] = red[4] + red[5] + red[6]  + red[7]  + bh[1];
        out[(size_t)r * NCLS + 2] = red[8] + red[9] + red[10] + red[11] + bh[2];
    }
}

// ---------------------------------------------------------------------------
extern "C" void kernel_launch(void* const* d_in, const int* in_sizes, int n_in,
                              void* d_out, int out_size, void* d_ws, size_t ws_size,
                              hipStream_t stream) {
    const float* hs      = (const float*)d_in[0];
    const float* W_down  = (const float*)d_in[1];
    const float* b_down  = (const float*)d_in[2];
    const float* W_ih0   = (const float*)d_in[3];
    const float* W_hh0   = (const float*)d_in[4];
    const float* b_ih0   = (const float*)d_in[5];
    const float* b_hh0   = (const float*)d_in[6];
    const float* W_ih1   = (const float*)d_in[7];
    const float* W_hh1   = (const float*)d_in[8];
    const float* b_ih1   = (const float*)d_in[9];
    const float* b_hh1   = (const float*)d_in[10];
    const float* W_lin1  = (const float*)d_in[11];
    const float* b_lin1  = (const float*)d_in[12];
    const float* gamma   = (const float*)d_in[13];
    const float* beta    = (const float*)d_in[14];
    const float* W_head  = (const float*)d_in[15];
    const float* b_head  = (const float*)d_in[16];
    const int*   gidx    = (const int*)d_in[17];
    float* out = (float*)d_out;

    char* ws = (char*)d_ws;
    const size_t MB = (size_t)1 << 20;
    float*        pooled   = (float*)(ws);                        // 4 MB fp32
    _Float16*     pooledh  = (_Float16*)(ws + 4 * MB);            // 2 MB
    _Float16*     xd_h     = (_Float16*)(ws + 6 * MB);            // 1 MB
    _Float16*     xW_h     = (_Float16*)(ws + 7 * MB);            // 3 MB
    _Float16*     ys1_h    = (_Float16*)(ws + 10 * MB);           // 1 MB
    float*        xln      = (float*)(ws + 11 * MB);              // 4 MB
    unsigned int* wp0      = (unsigned int*)(ws + 15 * MB);       // 1.5 MB
    unsigned int* wp1      = (unsigned int*)(ws + 15 * MB + 1536 * 1024); // 1.5 MB
    _Float16*     wdown_h  = (_Float16*)(ws + 18 * MB);           // 1 MB
    _Float16*     wih0_h   = (_Float16*)(ws + 19 * MB);           // 1.5 MB
    unsigned int* wip1     = (unsigned int*)(ws + 19 * MB + 1536 * 1024); // 1.5 MB
    _Float16*     wlin1_h  = (_Float16*)(ws + 22 * MB);           // 1 MB
    unsigned long long* hbuf0 = (unsigned long long*)(ws + 23 * MB); // 64 KB
    unsigned long long* hbuf1 = hbuf0 + 2 * BB * 256;                // 64 KB

    // zero the tagged h-exchange buffers (ws is poisoned before every launch;
    // garbage could alias a valid tag). 128 KB total.
    hipMemsetAsync(hbuf0, 0, 2 * 2 * BB * 256 * sizeof(unsigned long long), stream);

    // 1) pooling: fp32 residual + f16 GEMM input, layout (S,B,D)
    pool_kernel<<<BB * SS, 256, 0, stream>>>(hs, gidx, pooled, pooledh);

    // 2) fused weight prep (one dispatch)
    prep_kernel<<<2528, 256, 0, stream>>>(W_down, wdown_h, W_ih0, wih0_h,
                                          W_lin1, wlin1_h,
                                          W_hh0, wp0, W_hh1, wp1,
                                          W_ih1, wip1);

    // 3) down-projection: xd = pooled @ W_down^T + b_down  (f16 out)
    gemm_mfma_kernel<true><<<dim3(HH / 64, (SS * BB) / 64), 256, 0, stream>>>(
        pooledh, wdown_h, b_down, nullptr, xd_h, SS * BB, HH, DD);

    // 4) layer-0 input projection: xW = xd @ W_ih0^T + b_ih0  (f16 out)
    gemm_mfma_kernel<true><<<dim3(H3 / 64, (SS * BB) / 64), 256, 0, stream>>>(
        xd_h, wih0_h, b_ih0, nullptr, xW_h, SS * BB, H3, HH);

    // 5) fused two-layer recurrence (replaces gru0 + ih1 GEMM + gru1)
    gru_fused_kernel<<<BB * GPB, 256, 0, stream>>>(
        xW_h, wp0, b_hh0, wp1, b_hh1, wip1, b_ih1, ys1_h, hbuf0, hbuf1);

    // 6) up-projection + residual: xln = pooled + ys1 @ W_lin1^T + b_lin1 (fp32)
    gemm_mfma_kernel<false><<<dim3(DD / 64, (SS * BB) / 64), 256, 0, stream>>>(
        ys1_h, wlin1_h, b_lin1, pooled, xln, SS * BB, DD, HH);

    // 7) LayerNorm + head
    ln_head_kernel<<<BB * SS, 256, 0, stream>>>(xln, gamma, beta, W_head, b_head, out);
}

// Round 5
// 466.018 us; speedup vs baseline: 6.9628x; 6.9178x over previous
//
#include <hip/hip_runtime.h>
#include <hip/hip_bf16.h>
#include <cstddef>

// Problem constants
#define BB   16
#define LL   2048
#define DD   1024
#define SS   64
#define HH   512
#define H3   1536
#define NCLS 3
#define GPB  16   // WGs per batch in the GRU (each owns 32 of 512 hidden dims)

typedef _Float16 half2_t __attribute__((ext_vector_type(2)));
typedef _Float16 f16x8  __attribute__((ext_vector_type(8)));
typedef float    f32x4  __attribute__((ext_vector_type(4)));

static __device__ __forceinline__ half2_t u2h2(unsigned int u) {
    union { unsigned int u; half2_t h; } cv; cv.u = u; return cv.h;
}
static __device__ __forceinline__ unsigned short f2h(float f) {
    _Float16 h = (_Float16)f;
    union { _Float16 h; unsigned short u; } cv; cv.h = h; return cv.u;
}

// ---------------------------------------------------------------------------
// 1) Segment-mean pooling. One WG per (s,b); output (S,B,D) row r = s*16+b,
//    in fp32 (residual) AND f16 (GEMM input).
// ---------------------------------------------------------------------------
__global__ __launch_bounds__(256) void pool_kernel(
        const float* __restrict__ hs,      // (B, L, D)
        const int*   __restrict__ gidx,    // (B, L)
        float*       __restrict__ pooled,  // (S*B, D) fp32
        _Float16*    __restrict__ pooledh) // (S*B, D) f16
{
    const int r = blockIdx.x;
    const int b = r & 15;
    const int s = r >> 4;
    __shared__ int lst[LL];
    __shared__ int cnt;
    const int tid = threadIdx.x;
    if (tid == 0) cnt = 0;
    __syncthreads();
    const int* gi = gidx + b * LL;
    for (int l = tid; l < LL; l += 256) {
        if (gi[l] == s) { int p = atomicAdd(&cnt, 1); lst[p] = l; }
    }
    __syncthreads();
    const int c = cnt;
    const float* hb = hs + (size_t)b * LL * DD;
    const int d0 = tid * 4;
    float4 acc = make_float4(0.f, 0.f, 0.f, 0.f);
    for (int i = 0; i < c; ++i) {
        const float4 v = *(const float4*)(hb + (size_t)lst[i] * DD + d0);
        acc.x += v.x; acc.y += v.y; acc.z += v.z; acc.w += v.w;
    }
    const float inv = 1.0f / (float)c;
    float4 o = make_float4(acc.x * inv, acc.y * inv, acc.z * inv, acc.w * inv);
    *(float4*)(pooled + (size_t)r * DD + d0) = o;
    ushort4 oh;
    oh.x = f2h(o.x); oh.y = f2h(o.y); oh.z = f2h(o.z); oh.w = f2h(o.w);
    *(ushort4*)(pooledh + (size_t)r * DD + d0) = oh;
}

// ---------------------------------------------------------------------------
// 2) prep kernel (one dispatch):
//    [0,256):    W_down  fp32->f16
//    [256,640):  W_ih0   fp32->f16
//    [640,896):  W_lin1  fp32->f16
//    [896,1184): pack {W_hh0, W_hh1, W_ih1} -> wpk, layout
//                [p(16)][mat(3)][row rr(96)][e(8)][32 words], where word
//                (e,c,u) (c=chunk 0..7, u=0..3) holds f16 k-pair k2 =
//                32e + 4*((c+e)&7) + u of source row col = gate*512+p*32+jl
//                (rr = gate*32+jl). The (c+e)&7 rotation makes the runtime
//                h-broadcast LDS reads bank-conflict-free across e.
// ---------------------------------------------------------------------------
__global__ __launch_bounds__(256) void prep_kernel(
        const float* __restrict__ a, _Float16* __restrict__ da,
        const float* __restrict__ b, _Float16* __restrict__ db,
        const float* __restrict__ c, _Float16* __restrict__ dc,
        const float* __restrict__ Whh0,
        const float* __restrict__ Whh1,
        const float* __restrict__ Wih1,
        unsigned int* __restrict__ wpk)
{
    const int tid = threadIdx.x;
    int blk = blockIdx.x;
    if (blk < 896) {
        const float* s; _Float16* t;
        if (blk < 256)      { s = a; t = da; }
        else if (blk < 640) { s = b; t = db; blk -= 256; }
        else                { s = c; t = dc; blk -= 640; }
        const int i = (blk * 256 + tid) * 8;
        const float4 v0 = *(const float4*)(s + i);
        const float4 v1 = *(const float4*)(s + i + 4);
        ushort4 u0, u1;
        u0.x = f2h(v0.x); u0.y = f2h(v0.y); u0.z = f2h(v0.z); u0.w = f2h(v0.w);
        u1.x = f2h(v1.x); u1.y = f2h(v1.y); u1.z = f2h(v1.z); u1.w = f2h(v1.w);
        *(ushort4*)(t + i)     = u0;
        *(ushort4*)(t + i + 4) = u1;
        return;
    }
    // weight packing: 288 blocks; block -> (p, mat, 16-row band); 4096 words
    const int idx = blk - 896;
    const int p   = idx / 18;
    const int rem = idx % 18;
    const int mat = rem / 6;
    const int rb  = rem % 6;
    const float* W = (mat == 0) ? Whh0 : (mat == 1) ? Whh1 : Wih1;
#pragma unroll
    for (int w16 = 0; w16 < 16; ++w16) {
        const int wordid = tid * 16 + w16;          // 0..4095
        const int rr   = rb * 16 + (wordid >> 8);   // 0..95
        const int widx = wordid & 255;
        const int e  = widx >> 5;
        const int r2 = widx & 31;
        const int ch = r2 >> 2;
        const int u  = r2 & 3;
        const int k2 = 32 * e + 4 * ((ch + e) & 7) + u;
        const int gate = rr >> 5, jl = rr & 31;
        const int col  = gate * HH + p * 32 + jl;
        const float lo = W[(size_t)col * HH + 2 * k2];
        const float hi = W[(size_t)col * HH + 2 * k2 + 1];
        wpk[(((size_t)p * 3 + mat) * 96 + rr) * 256 + widx] =
            (unsigned int)f2h(lo) | ((unsigned int)f2h(hi) << 16);
    }
}

// ---------------------------------------------------------------------------
// 3) f16 MFMA GEMM: C[M,N] = A[M,K] @ W[N,K]^T + bias[N] (+resid, fp32 out)
//    or f16 out. 64x64 tile per WG (4 waves; wave w = 16-row strip), K-step 32.
// ---------------------------------------------------------------------------
template <bool F16OUT>
__global__ __launch_bounds__(256) void gemm_mfma_kernel(
        const _Float16* __restrict__ A,
        const _Float16* __restrict__ W,
        const float*    __restrict__ bias,
        const float*    __restrict__ resid,   // nullable, only for fp32 out
        void*           __restrict__ C,
        int M, int N, int K)
{
    const int tid  = threadIdx.x;
    const int wv   = tid >> 6;
    const int lane = tid & 63;
    const int m0 = blockIdx.y * 64 + wv * 16;
    const int n0 = blockIdx.x * 64;
    const int l15 = lane & 15;
    const int ko  = (lane >> 4) * 8;

    const _Float16* Ap = A + (size_t)(m0 + l15) * K + ko;
    const _Float16* Wpt = W + (size_t)(n0 + l15) * K + ko;

    f32x4 acc[4] = {};
    for (int k0 = 0; k0 < K; k0 += 32) {
        const f16x8 av = *(const f16x8*)(Ap + k0);
#pragma unroll
        for (int nb = 0; nb < 4; ++nb) {
            const f16x8 bq = *(const f16x8*)(Wpt + (size_t)nb * 16 * K + k0);
            acc[nb] = __builtin_amdgcn_mfma_f32_16x16x32_f16(av, bq, acc[nb], 0, 0, 0);
        }
    }
    const int crow = m0 + (lane >> 4) * 4;
#pragma unroll
    for (int nb = 0; nb < 4; ++nb) {
        const int col = n0 + nb * 16 + l15;
        const float bb = bias[col];
#pragma unroll
        for (int rg = 0; rg < 4; ++rg) {
            float v = acc[nb][rg] + bb;
            const size_t off = (size_t)(crow + rg) * N + col;
            if (F16OUT) {
                ((_Float16*)C)[off] = (_Float16)v;
            } else {
                if (resid) v += resid[off];
                ((float*)C)[off] = v;
            }
        }
    }
}

// ---------------------------------------------------------------------------
// 4) Fused two-layer GRU, v10. 256 WGs = (b,p), 768 threads (12 waves).
//    Thread (rr = tid>>3, e = tid&7) owns a 64-elem k-slice of gate-row rr
//    for all three matrices: w0/w1/wI = 24 uint4 = 96 VGPRs (v8/v9's 320-dword
//    demand spilled; 96+~45 fits the 170-VGPR cap from launch_bounds(768,3)).
//    8-way k-split reduced via shfl_xor(1,2,4). Chunk rotation (c+e)&7 makes
//    the h-broadcast LDS reads conflict-free. Handshake identical to v8/v9
//    (tagged 8B words, dual poll) -- protocol verified by two passing runs.
//    Iteration t: layer-0 step t, layer-1 step t-1; ih1 projection fused.
// ---------------------------------------------------------------------------
__global__ __launch_bounds__(768, 3) void gru_fused_kernel(
        const _Float16*     __restrict__ xW0,   // (S*B, 1536) f16 (layer-0 xW)
        const unsigned int* __restrict__ wpk,   // (16,3,96,256) packed f16 pairs
        const float*        __restrict__ bhh0,  // (1536)
        const float*        __restrict__ bhh1,  // (1536)
        const float*        __restrict__ bih1,  // (1536)
        _Float16*           __restrict__ ys1,   // (S*B, 512) f16 (layer-1 out)
        unsigned long long* __restrict__ hbuf0, // [2][16][256] {tag,pk}
        unsigned long long* __restrict__ hbuf1) // [2][16][256] {tag,pk}
{
    __shared__ __align__(16) unsigned int h0ls[256];
    __shared__ __align__(16) unsigned int h1ls[256];
    __shared__ float dots0[96];
    __shared__ float dots1[128];   // r[0,32) z[32,64) n_x[64,96) n_h[96,128)

    const int wg  = blockIdx.x;
    const int b   = wg & 15;
    const int p   = wg >> 4;
    const int tid = threadIdx.x;
    const int rr  = tid >> 3;           // 0..95 gate-row
    const int e   = tid & 7;            // k-slice
    const int gate = rr >> 5;
    const int jl   = rr & 31;
    const int col  = gate * HH + p * 32 + jl;

    const float bias0 = bhh0[col];
    const float biasH = bhh1[col];
    const float biasI = bih1[col];

    uint4 w0r[8], w1r[8], wIr[8];
    {
        const uint4* gbase =
            (const uint4*)(wpk + (((size_t)p * 3) * 96 + rr) * 256) + e * 8;
        const int ms = 96 * 256 / 4;    // uint4 stride between matrices
#pragma unroll
        for (int q = 0; q < 8; ++q) w0r[q] = gbase[q];
#pragma unroll
        for (int q = 0; q < 8; ++q) w1r[q] = gbase[ms + q];
#pragma unroll
        for (int q = 0; q < 8; ++q) wIr[q] = gbase[2 * ms + q];
    }
    if (tid < 256) { h0ls[tid] = 0u; h1ls[tid] = 0u; }
    float h0_own = 0.f, h1_own = 0.f;
    __syncthreads();

    for (int t = 0; t <= SS; ++t) {
        // ---- layer-0 xW prefetch (no h dependency; hides under poll) ----
        float xr = 0.f, xz = 0.f, xn = 0.f;
        if (t < SS && tid < 32) {
            const int row = t * BB + b;
            const int j = p * 32 + tid;
            xr = (float)xW0[(size_t)row * H3 + j];
            xz = (float)xW0[(size_t)row * H3 + HH + j];
            xn = (float)xW0[(size_t)row * H3 + 2 * HH + j];
        }

        // ---- dual tagged poll: h0_{t-1} (tag t) and h1_{t-2} (tag t-1) ----
        if (tid < 256) {
            const unsigned long long* s0 =
                hbuf0 + ((size_t)(((t - 1) & 1) * BB + b)) * 256 + tid;
            const unsigned long long* s1 =
                hbuf1 + ((size_t)((t & 1) * BB + b)) * 256 + tid;
            unsigned long long v0 = 0ull, v1 = 0ull;
            bool d0 = (t == 0), d1 = (t <= 1);
            while (!(d0 && d1)) {
                unsigned long long av = 0ull, cv = 0ull;
                if (!d0) av = __hip_atomic_load(s0, __ATOMIC_RELAXED,
                                                __HIP_MEMORY_SCOPE_AGENT);
                if (!d1) cv = __hip_atomic_load(s1, __ATOMIC_RELAXED,
                                                __HIP_MEMORY_SCOPE_AGENT);
                if (!d0 && (unsigned int)(av >> 32) == (unsigned int)t) {
                    v0 = av; d0 = true;
                }
                if (!d1 && (unsigned int)(cv >> 32) == (unsigned int)(t - 1)) {
                    v1 = cv; d1 = true;
                }
                if (!(d0 && d1)) __builtin_amdgcn_s_sleep(1);
            }
            if (t > 0) h0ls[tid] = (unsigned int)v0;
            if (t > 1) h1ls[tid] = (unsigned int)v1;
        }
        __syncthreads();                                   // (A)

        // ---- dots: hh0 (h0), hh1 (h1), ih1 (h0); all 768 threads ----
        {
            float A0 = 0.f, A1 = 0.f, A2 = 0.f, A3 = 0.f;   // hh0
            float B0 = 0.f, B1 = 0.f, B2 = 0.f, B3 = 0.f;   // hh1
            float C0 = 0.f, C1 = 0.f, C2 = 0.f, C3 = 0.f;   // ih1
            const uint4* h0p = (const uint4*)h0ls;
            const uint4* h1p = (const uint4*)h1ls;
#pragma unroll
            for (int ch = 0; ch < 8; ++ch) {
                const int hidx = e * 8 + ((ch + e) & 7);
                const uint4 h0v = h0p[hidx];
                const uint4 h1v = h1p[hidx];
                A0 = __builtin_amdgcn_fdot2(u2h2(w0r[ch].x), u2h2(h0v.x), A0, false);
                A1 = __builtin_amdgcn_fdot2(u2h2(w0r[ch].y), u2h2(h0v.y), A1, false);
                A2 = __builtin_amdgcn_fdot2(u2h2(w0r[ch].z), u2h2(h0v.z), A2, false);
                A3 = __builtin_amdgcn_fdot2(u2h2(w0r[ch].w), u2h2(h0v.w), A3, false);
                B0 = __builtin_amdgcn_fdot2(u2h2(w1r[ch].x), u2h2(h1v.x), B0, false);
                B1 = __builtin_amdgcn_fdot2(u2h2(w1r[ch].y), u2h2(h1v.y), B1, false);
                B2 = __builtin_amdgcn_fdot2(u2h2(w1r[ch].z), u2h2(h1v.z), B2, false);
                B3 = __builtin_amdgcn_fdot2(u2h2(w1r[ch].w), u2h2(h1v.w), B3, false);
                C0 = __builtin_amdgcn_fdot2(u2h2(wIr[ch].x), u2h2(h0v.x), C0, false);
                C1 = __builtin_amdgcn_fdot2(u2h2(wIr[ch].y), u2h2(h0v.y), C1, false);
                C2 = __builtin_amdgcn_fdot2(u2h2(wIr[ch].z), u2h2(h0v.z), C2, false);
                C3 = __builtin_amdgcn_fdot2(u2h2(wIr[ch].w), u2h2(h0v.w), C3, false);
            }
            float sA = (A0 + A1) + (A2 + A3);
            float sB = (B0 + B1) + (B2 + B3);
            float sC = (C0 + C1) + (C2 + C3);
            sA += __shfl_xor(sA, 1, 64); sA += __shfl_xor(sA, 2, 64); sA += __shfl_xor(sA, 4, 64);
            sB += __shfl_xor(sB, 1, 64); sB += __shfl_xor(sB, 2, 64); sB += __shfl_xor(sB, 4, 64);
            sC += __shfl_xor(sC, 1, 64); sC += __shfl_xor(sC, 2, 64); sC += __shfl_xor(sC, 4, 64);
            if (e == 0) {
                dots0[rr] = sA + bias0;
                if (gate < 2) {
                    dots1[gate * 32 + jl] = sB + sC + biasI + biasH;
                } else {
                    dots1[64 + jl] = sC + biasI;
                    dots1[96 + jl] = sB + biasH;
                }
            }
        }
        __syncthreads();                                   // (B)

        // ---- layer-0 gates (wave0 lanes 0..31): step t ----
        if (t < SS && tid < 32) {
            const float ar = dots0[tid];
            const float az = dots0[32 + tid];
            const float an = dots0[64 + tid];
            const float rg = 1.f / (1.f + __expf(-(xr + ar)));
            const float zg = 1.f / (1.f + __expf(-(xz + az)));
            const float nn = xn + rg * an;
            const float ev = __expf(-2.f * nn);
            const float ng = (1.f - ev) / (1.f + ev);        // tanh
            const float hnew = (1.f - zg) * ng + zg * h0_own;
            h0_own = hnew;
            const float other = __shfl_xor(hnew, 1, 64);
            if ((tid & 1) == 0) {
                const unsigned int pk = (unsigned int)f2h(hnew)
                                      | ((unsigned int)f2h(other) << 16);
                const unsigned long long val =
                    ((unsigned long long)(unsigned int)(t + 1) << 32) | pk;
                __hip_atomic_store(
                    hbuf0 + ((size_t)((t & 1) * BB + b)) * 256 + p * 16 + (tid >> 1),
                    val, __ATOMIC_RELAXED, __HIP_MEMORY_SCOPE_AGENT);
            }
        }
        // ---- layer-1 gates (wave1 lanes 0..31): step t-1 ----
        if (t > 0 && tid >= 64 && tid < 96) {
            const int j = tid - 64;
            const float ar = dots1[j];
            const float az = dots1[32 + j];
            const float nx = dots1[64 + j];
            const float nh = dots1[96 + j];
            const float rg = 1.f / (1.f + __expf(-ar));
            const float zg = 1.f / (1.f + __expf(-az));
            const float nn = nx + rg * nh;
            const float ev = __expf(-2.f * nn);
            const float ng = (1.f - ev) / (1.f + ev);        // tanh
            const float hnew = (1.f - zg) * ng + zg * h1_own;
            h1_own = hnew;
            ys1[(size_t)((t - 1) * BB + b) * HH + p * 32 + j] = (_Float16)hnew;
            const float other = __shfl_xor(hnew, 1, 64);
            if ((j & 1) == 0) {
                const unsigned int pk = (unsigned int)f2h(hnew)
                                      | ((unsigned int)f2h(other) << 16);
                const unsigned long long val =
                    ((unsigned long long)(unsigned int)t << 32) | pk;
                __hip_atomic_store(
                    hbuf1 + ((size_t)(((t - 1) & 1) * BB + b)) * 256 + p * 16 + (j >> 1),
                    val, __ATOMIC_RELAXED, __HIP_MEMORY_SCOPE_AGENT);
            }
        }
        // no trailing barrier: barrier (B) orders this iter's LDS reads
        // before next iter's poll writes; hbuf slot reuse is gated by the
        // producers' own polls (see v8 analysis; protocol passed twice).
    }
}

// ---------------------------------------------------------------------------
// 5) Fused LayerNorm + classification head. One WG per output row.
// ---------------------------------------------------------------------------
__global__ __launch_bounds__(256) void ln_head_kernel(
        const float* __restrict__ X,      // (S*B, D), row = s*16+b
        const float* __restrict__ gamma,
        const float* __restrict__ beta,
        const float* __restrict__ Wh,     // (3, 1024)
        const float* __restrict__ bh,     // (3)
        float*       __restrict__ out)    // (B*S, 3)
{
    __shared__ float red[12];
    const int r  = blockIdx.x;            // b*64 + s
    const int bI = r >> 6;
    const int s  = r & 63;
    const float* x = X + (size_t)(s * BB + bI) * DD;
    const int tid = threadIdx.x;
    const float4 v = *(const float4*)(x + tid * 4);
    float sum = v.x + v.y + v.z + v.w;
    float ss  = v.x * v.x + v.y * v.y + v.z * v.z + v.w * v.w;
#pragma unroll
    for (int o = 32; o > 0; o >>= 1) {
        sum += __shfl_down(sum, o, 64);
        ss  += __shfl_down(ss,  o, 64);
    }
    const int lane = tid & 63, w = tid >> 6;
    if (lane == 0) { red[w] = sum; red[4 + w] = ss; }
    __syncthreads();
    const float tsum = red[0] + red[1] + red[2] + red[3];
    const float tss  = red[4] + red[5] + red[6] + red[7];
    const float mu  = tsum * (1.f / (float)DD);
    const float var = tss * (1.f / (float)DD) - mu * mu;
    const float inv = rsqrtf(var + 1e-5f);
    const float4 g  = *(const float4*)(gamma + tid * 4);
    const float4 be = *(const float4*)(beta + tid * 4);
    float y0 = (v.x - mu) * inv * g.x + be.x;
    float y1 = (v.y - mu) * inv * g.y + be.y;
    float y2 = (v.z - mu) * inv * g.z + be.z;
    float y3 = (v.w - mu) * inv * g.w + be.w;
    const float4 w0 = *(const float4*)(Wh + 0 * DD + tid * 4);
    const float4 w1 = *(const float4*)(Wh + 1 * DD + tid * 4);
    const float4 w2 = *(const float4*)(Wh + 2 * DD + tid * 4);
    float p0 = y0 * w0.x + y1 * w0.y + y2 * w0.z + y3 * w0.w;
    float p1 = y0 * w1.x + y1 * w1.y + y2 * w1.z + y3 * w1.w;
    float p2 = y0 * w2.x + y1 * w2.y + y2 * w2.z + y3 * w2.w;
#pragma unroll
    for (int o = 32; o > 0; o >>= 1) {
        p0 += __shfl_down(p0, o, 64);
        p1 += __shfl_down(p1, o, 64);
        p2 += __shfl_down(p2, o, 64);
    }
    __syncthreads();
    if (lane == 0) { red[w] = p0; red[4 + w] = p1; red[8 + w] = p2; }
    __syncthreads();
    if (tid == 0) {
        out[(size_t)r * NCLS + 0] = red[0] + red[1] + red[2]  + red[3]  + bh[0];
        out[(size_t)r * NCLS + 1] = red[4] + red[5] + red[6]  + red[7]  + bh[1];
        out[(size_t)r * NCLS + 2] = red[8] + red[9] + red[10] + red[11] + bh[2];
    }
}

// ---------------------------------------------------------------------------
extern "C" void kernel_launch(void* const* d_in, const int* in_sizes, int n_in,
                              void* d_out, int out_size, void* d_ws, size_t ws_size,
                              hipStream_t stream) {
    const float* hs      = (const float*)d_in[0];
    const float* W_down  = (const float*)d_in[1];
    const float* b_down  = (const float*)d_in[2];
    const float* W_ih0   = (const float*)d_in[3];
    const float* W_hh0   = (const float*)d_in[4];
    const float* b_ih0   = (const float*)d_in[5];
    const float* b_hh0   = (const float*)d_in[6];
    const float* W_ih1   = (const float*)d_in[7];
    const float* W_hh1   = (const float*)d_in[8];
    const float* b_ih1   = (const float*)d_in[9];
    const float* b_hh1   = (const float*)d_in[10];
    const float* W_lin1  = (const float*)d_in[11];
    const float* b_lin1  = (const float*)d_in[12];
    const float* gamma   = (const float*)d_in[13];
    const float* beta    = (const float*)d_in[14];
    const float* W_head  = (const float*)d_in[15];
    const float* b_head  = (const float*)d_in[16];
    const int*   gidx    = (const int*)d_in[17];
    float* out = (float*)d_out;

    char* ws = (char*)d_ws;
    const size_t MB = (size_t)1 << 20;
    float*        pooled   = (float*)(ws);                        // 4 MB fp32
    _Float16*     pooledh  = (_Float16*)(ws + 4 * MB);            // 2 MB
    _Float16*     xd_h     = (_Float16*)(ws + 6 * MB);            // 1 MB
    _Float16*     xW_h     = (_Float16*)(ws + 7 * MB);            // 3 MB
    _Float16*     ys1_h    = (_Float16*)(ws + 10 * MB);           // 1 MB
    float*        xln      = (float*)(ws + 11 * MB);              // 4 MB
    unsigned int* wpk      = (unsigned int*)(ws + 15 * MB);       // 4.5 MB
    _Float16*     wdown_h  = (_Float16*)(ws + 19 * MB + 512 * 1024);  // 1 MB
    _Float16*     wih0_h   = (_Float16*)(ws + 20 * MB + 512 * 1024);  // 1.5 MB
    _Float16*     wlin1_h  = (_Float16*)(ws + 22 * MB);           // 1 MB
    unsigned long long* hbuf0 = (unsigned long long*)(ws + 23 * MB); // 64 KB
    unsigned long long* hbuf1 = hbuf0 + 2 * BB * 256;                // 64 KB

    // zero the tagged h-exchange buffers (ws is poisoned before every launch;
    // garbage could alias a valid tag). 128 KB total.
    hipMemsetAsync(hbuf0, 0, 2 * 2 * BB * 256 * sizeof(unsigned long long), stream);

    // 1) pooling: fp32 residual + f16 GEMM input, layout (S,B,D)
    pool_kernel<<<BB * SS, 256, 0, stream>>>(hs, gidx, pooled, pooledh);

    // 2) fused weight prep (one dispatch)
    prep_kernel<<<1184, 256, 0, stream>>>(W_down, wdown_h, W_ih0, wih0_h,
                                          W_lin1, wlin1_h,
                                          W_hh0, W_hh1, W_ih1, wpk);

    // 3) down-projection: xd = pooled @ W_down^T + b_down  (f16 out)
    gemm_mfma_kernel<true><<<dim3(HH / 64, (SS * BB) / 64), 256, 0, stream>>>(
        pooledh, wdown_h, b_down, nullptr, xd_h, SS * BB, HH, DD);

    // 4) layer-0 input projection: xW = xd @ W_ih0^T + b_ih0  (f16 out)
    gemm_mfma_kernel<true><<<dim3(H3 / 64, (SS * BB) / 64), 256, 0, stream>>>(
        xd_h, wih0_h, b_ih0, nullptr, xW_h, SS * BB, H3, HH);

    // 5) fused two-layer recurrence (replaces gru0 + ih1 GEMM + gru1)
    gru_fused_kernel<<<BB * GPB, 768, 0, stream>>>(
        xW_h, wpk, b_hh0, b_hh1, b_ih1, ys1_h, hbuf0, hbuf1);

    // 6) up-projection + residual: xln = pooled + ys1 @ W_lin1^T + b_lin1 (fp32)
    gemm_mfma_kernel<false><<<dim3(DD / 64, (SS * BB) / 64), 256, 0, stream>>>(
        ys1_h, wlin1_h, b_lin1, pooled, xln, SS * BB, DD, HH);

    // 7) LayerNorm + head
    ln_head_kernel<<<BB * SS, 256, 0, stream>>>(xln, gamma, beta, W_head, b_head, out);
}